// Round 6
// baseline (180.716 us; speedup 1.0000x reference)
//
#include <hip/hip_runtime.h>
#include <hip/hip_bf16.h>
#include <cstdint>

// Problem constants
#define NB   32      // batch
#define NC   256     // z channels
#define NE   128     // embed dim
#define NS   256     // H*W pixels per batch
#define NV   4096    // vocab
#define NP   8192    // total pixels
#define NSPLIT 8     // vocab splits (512 codes each)

typedef unsigned short ushort_t;
typedef __attribute__((ext_vector_type(8))) short bf16x8;
typedef __attribute__((ext_vector_type(8))) unsigned short us8;
typedef __attribute__((ext_vector_type(4))) float f32x4;

__device__ __forceinline__ ushort_t f2bf(float f) {
    __hip_bfloat16 h = __float2bfloat16(f);
    ushort_t u; __builtin_memcpy(&u, &h, 2); return u;
}
__device__ __forceinline__ unsigned asu(float f) { unsigned u; __builtin_memcpy(&u,&f,4); return u; }
__device__ __forceinline__ float    asf(unsigned u) { float f; __builtin_memcpy(&f,&u,4); return f; }

// ---------------------------------------------------------------------------
// K0: pack emb hi-bf16 into Bpack (MFMA B-frag order) + cnorm. (Validated.)
// Bpack (ushort units): [(G*4 + ks)*512 + L*8 + j],
//   element = emb[code = G*16 + (L&15)][k = ks*32 + (L>>4)*8 + j]
// ---------------------------------------------------------------------------
__global__ __launch_bounds__(256) void pack_emb(
    const float* __restrict__ emb, ushort_t* __restrict__ Bpack,
    float* __restrict__ cnorm)
{
    const int t = threadIdx.x;
    const int v     = blockIdx.x * 32 + (t >> 3);
    const int chunk = t & 7;
    const float4* rp = (const float4*)(emb + (size_t)v * NE + chunk * 16);
    float4 x0 = rp[0], x1 = rp[1], x2 = rp[2], x3 = rp[3];
    float xs[16] = { x0.x, x0.y, x0.z, x0.w, x1.x, x1.y, x1.z, x1.w,
                     x2.x, x2.y, x2.z, x2.w, x3.x, x3.y, x3.z, x3.w };
    us8 h0, h1;
    float nn = 0.f;
#pragma unroll
    for (int j = 0; j < 8; j++) {
        nn = fmaf(xs[j], xs[j], nn);
        h0[j] = f2bf(xs[j]);
    }
#pragma unroll
    for (int j = 0; j < 8; j++) {
        nn = fmaf(xs[8 + j], xs[8 + j], nn);
        h1[j] = f2bf(xs[8 + j]);
    }
    nn += __shfl_xor(nn, 1);
    nn += __shfl_xor(nn, 2);
    nn += __shfl_xor(nn, 4);
    if (chunk == 0) cnorm[v] = 0.5f * nn;

    const int G  = v >> 4;
    const int ks = chunk >> 1;
    const int q0 = (chunk & 1) * 2;
    const int L0 = (v & 15) | (q0 << 4);
    const int L1 = (v & 15) | ((q0 + 1) << 4);
    *(us8*)(Bpack + ((size_t)G * 4 + ks) * 512 + L0 * 8) = h0;
    *(us8*)(Bpack + ((size_t)G * 4 + ks) * 512 + L1 * 8) = h1;
}

// ---------------------------------------------------------------------------
// K_main v2: whole pixel pipeline, block = 16 pixels (512 blocks x 512 thr
// -> 2 blocks/CU, 4 waves/SIMD; round-5 was 1 block/CU = 2 waves/SIMD and
// latency-bound at 21% occupancy).
//   P1 stage z_e tile (ze[256][20], float4)
//   P2 z-GEMM f32: thread=(px-quad, e); zl[16][132] + out_z
//   P3 MFMA scoring, 2 splits in flight (wq), wv quad = validated score_mfma
//      layout with mt=1; top-4/split -> cand[8][16][4]
//   P4 exact f64 rescore: 1 cand/thread (16px x 32cand), 4-way partials,
//      32-lane shfl argmax, tie -> lowest idx
//   P5 gather z_q -> eg (aliases zl) + out_zq
//   P6 post_conv (c = t&255, ph = t>>8 -> 8 px each)
// LDS arena 31040 B: ze region (20480) hosts r1/r2/t4b after P2 dies.
// ---------------------------------------------------------------------------
#define ZE_STR   20
#define ZL_STR   132
#define ZE_OFF   0           // 256*20*4 = 20480
#define R1_OFF   0           // 2*64*17*4 = 8704   (alias ze, dead after P2)
#define R2_OFF   8704        // 8704               (alias ze)
#define T4B_OFF  17408       // 2*16*4*4*4 = 2048  (alias ze)
#define ZL_OFF   20480       // 16*132*4 = 8448    (eg aliases after P4)
#define CAND_OFF 28928       // 8*16*4*4 = 2048
#define TOK_OFF  30976       // 16*4 = 64
#define SM_SIZE  31040

__global__ __launch_bounds__(512, 2) void vq_main(
    const float* __restrict__ z_e, const float* __restrict__ pre_w,
    const float* __restrict__ pre_b, const float* __restrict__ emb,
    const float* __restrict__ post_w, const float* __restrict__ post_b,
    const ushort_t* __restrict__ Bpack, const float* __restrict__ cnorm,
    float* __restrict__ out_z, float* __restrict__ out_zq,
    float* __restrict__ out_rec)
{
    __shared__ __align__(16) char smraw[SM_SIZE];
    float* ze   = (float*)(smraw + ZE_OFF);
    float* r1   = (float*)(smraw + R1_OFF);
    float* r2   = (float*)(smraw + R2_OFF);
    float* t4b  = (float*)(smraw + T4B_OFF);
    float* zl   = (float*)(smraw + ZL_OFF);
    float* eg   = (float*)(smraw + ZL_OFF);    // alias, used after P4
    int*   cand = (int*)(smraw + CAND_OFF);
    int*   tok  = (int*)(smraw + TOK_OFF);

    const int t  = threadIdx.x;
    const int b  = blockIdx.x >> 4;
    const int s0 = (blockIdx.x & 15) * 16;

    // ================= P1: stage z_e[b, :, s0..s0+16] (float4) ========
    for (int idx = t; idx < NC * 4; idx += 512) {
        int c = idx >> 2, q = idx & 3;
        *(float4*)&ze[c * ZE_STR + q * 4] =
            *(const float4*)(z_e + ((size_t)b * NC + c) * NS + s0 + q * 4);
    }
    __syncthreads();

    // ================= P2: z-GEMM (f32) ===============================
    {
        const int pg = t >> 7;       // px quad 0..3
        const int e  = t & 127;      // embed row
        const float* wr = pre_w + (size_t)e * NC;
        float a0 = 0.f, a1 = 0.f, a2 = 0.f, a3 = 0.f;
#pragma unroll 2
        for (int c = 0; c < NC; c += 4) {
            float4 w4 = *(const float4*)(wr + c);
            float4 z4;
            z4 = *(const float4*)&ze[(c + 0) * ZE_STR + pg * 4];
            a0 = fmaf(w4.x, z4.x, a0); a1 = fmaf(w4.x, z4.y, a1);
            a2 = fmaf(w4.x, z4.z, a2); a3 = fmaf(w4.x, z4.w, a3);
            z4 = *(const float4*)&ze[(c + 1) * ZE_STR + pg * 4];
            a0 = fmaf(w4.y, z4.x, a0); a1 = fmaf(w4.y, z4.y, a1);
            a2 = fmaf(w4.y, z4.z, a2); a3 = fmaf(w4.y, z4.w, a3);
            z4 = *(const float4*)&ze[(c + 2) * ZE_STR + pg * 4];
            a0 = fmaf(w4.z, z4.x, a0); a1 = fmaf(w4.z, z4.y, a1);
            a2 = fmaf(w4.z, z4.z, a2); a3 = fmaf(w4.z, z4.w, a3);
            z4 = *(const float4*)&ze[(c + 3) * ZE_STR + pg * 4];
            a0 = fmaf(w4.w, z4.x, a0); a1 = fmaf(w4.w, z4.y, a1);
            a2 = fmaf(w4.w, z4.z, a2); a3 = fmaf(w4.w, z4.w, a3);
        }
        const float bias = pre_b[e];
        a0 += bias; a1 += bias; a2 += bias; a3 += bias;
        zl[(pg * 4 + 0) * ZL_STR + e] = a0;
        zl[(pg * 4 + 1) * ZL_STR + e] = a1;
        zl[(pg * 4 + 2) * ZL_STR + e] = a2;
        zl[(pg * 4 + 3) * ZL_STR + e] = a3;
        float4 o = { a0, a1, a2, a3 };
        *(float4*)(out_z + ((size_t)b * NE + e) * NS + s0 + pg * 4) = o;
    }
    __syncthreads();

    // ================= P3: MFMA scoring + top-4/split =================
    const int wave = t >> 6, lane = t & 63;
    const int am = lane & 15, aq = lane >> 4;

    // A-fragments (validated packing, 16 rows -> mt dimension removed)
    bf16x8 ah[4];
#pragma unroll
    for (int ks = 0; ks < 4; ks++) {
        const unsigned* src = (const unsigned*)(zl + am * ZL_STR + ks * 32 + aq * 8);
        union { unsigned u[4]; bf16x8 v; } pk;
#pragma unroll
        for (int pr = 0; pr < 4; pr++)
            pk.u[pr] = (src[2 * pr + 1] & 0xFFFF0000u) | (src[2 * pr] >> 16);
        ah[ks] = pk.v;
    }

    const int wq = wave >> 2;      // split half within pair
    const int wv = wave & 3;       // plays validated kernel's "wave"

    for (int sp = 0; sp < NSPLIT; sp += 2) {
        const int split = sp + wq;
        const int Gbase = split * 32 + wv * 8;
        float cn[8];
#pragma unroll
        for (int cgi = 0; cgi < 8; cgi++)
            cn[cgi] = cnorm[(Gbase + cgi) * 16 + am];

        float b1v[4], b2v[4];
#pragma unroll
        for (int i = 0; i < 4; i++) { b1v[i] = -1e30f; b2v[i] = -1e30f; }

        bf16x8 bh[4], bhn[4];
#pragma unroll
        for (int ks = 0; ks < 4; ks++)
            bh[ks] = *(const bf16x8*)(Bpack + ((size_t)Gbase * 4 + ks) * 512 + lane * 8);

        for (int cgi = 0; cgi < 8; cgi++) {
            if (cgi < 7) {
#pragma unroll
                for (int ks = 0; ks < 4; ks++)
                    bhn[ks] = *(const bf16x8*)(Bpack + ((size_t)(Gbase + cgi + 1) * 4 + ks) * 512 + lane * 8);
            }
            f32x4 acc = (f32x4){0.f, 0.f, 0.f, 0.f};
#pragma unroll
            for (int ks = 0; ks < 4; ks++)
                acc = __builtin_amdgcn_mfma_f32_16x16x32_bf16(ah[ks], bh[ks], acc, 0, 0, 0);

#pragma unroll
            for (int reg = 0; reg < 4; reg++) {
                float sc = acc[reg] - cn[cgi];
                float ev = asf((asu(sc) & ~7u) | (unsigned)cgi);
                b2v[reg] = fmaxf(b2v[reg], fminf(ev, b1v[reg]));
                b1v[reg] = fmaxf(b1v[reg], ev);
            }
#pragma unroll
            for (int ks = 0; ks < 4; ks++) bh[ks] = bhn[ks];
        }

        const int slot = wv * 16 + am;
#pragma unroll
        for (int reg = 0; reg < 4; reg++) {
            int px = aq * 4 + reg;
            r1[(wq * 64 + slot) * 17 + px] = b1v[reg];
            r2[(wq * 64 + slot) * 17 + px] = b2v[reg];
        }
        __syncthreads();

        if (t < 128) {
            const int wq2 = t >> 6, rem = t & 63;
            const int px = rem >> 2, ch = rem & 3;
            float t1 = -1e30f, t2 = -1e30f, t3 = -1e30f, t4 = -1e30f;
            for (int i = 0; i < 16; i++) {
                int sl = ch * 16 + i;
#pragma unroll
                for (int e = 0; e < 2; e++) {
                    float raw = e ? r2[(wq2 * 64 + sl) * 17 + px]
                                  : r1[(wq2 * 64 + sl) * 17 + px];
                    unsigned vb = asu(raw);
                    float v = asf((vb & ~511u) | ((unsigned)sl << 3) | (vb & 7u));
                    t4 = fmaxf(t4, fminf(v, t3));
                    t3 = fmaxf(t3, fminf(v, t2));
                    t2 = fmaxf(t2, fminf(v, t1));
                    t1 = fmaxf(t1, v);
                }
            }
            float* dst = t4b + ((wq2 * 16 + px) * 4 + ch) * 4;
            dst[0] = t1; dst[1] = t2; dst[2] = t3; dst[3] = t4;
        }
        __syncthreads();

        if (t < 32) {
            const int wq2 = t >> 4, px = t & 15;
            float u1 = -1e30f, u2 = -1e30f, u3 = -1e30f, u4 = -1e30f;
            for (int ch = 0; ch < 4; ch++) {
#pragma unroll
                for (int j = 0; j < 4; j++) {
                    float v = t4b[((wq2 * 16 + px) * 4 + ch) * 4 + j];
                    u4 = fmaxf(u4, fminf(v, u3));
                    u3 = fmaxf(u3, fminf(v, u2));
                    u2 = fmaxf(u2, fminf(v, u1));
                    u1 = fmaxf(u1, v);
                }
            }
            const int spw = sp + wq2;
            float uu[4] = { u1, u2, u3, u4 };
#pragma unroll
            for (int j = 0; j < 4; j++) {
                unsigned bits = asu(uu[j]) & 511u;
                int w = (int)(bits >> 7), res = (int)((bits >> 3) & 15u), cg = (int)(bits & 7u);
                cand[(spw * 16 + px) * 4 + j] = spw * 512 + (w * 8 + cg) * 16 + res;
            }
        }
        __syncthreads();
    }

    // ================= P4: exact f64 rescore (1 cand/thread) ==========
    {
        const int il = t >> 5;   // px 0..15
        const int cc = t & 31;   // candidate 0..31
        const int split = cc >> 2, slot = cc & 3;
        const int idx = cand[(split * 16 + il) * 4 + slot];
        const float* er = emb + (size_t)idx * NE;
        const float* zr = zl + il * ZL_STR;

        double d0 = 0.0, d1 = 0.0, d2 = 0.0, d3 = 0.0;
        double n0 = 0.0, n1 = 0.0, n2 = 0.0, n3 = 0.0;
#pragma unroll
        for (int k = 0; k < NE; k += 16) {
            float4 e0 = *(const float4*)(er + k + 0);
            float4 e1 = *(const float4*)(er + k + 4);
            float4 e2 = *(const float4*)(er + k + 8);
            float4 e3 = *(const float4*)(er + k + 12);
            float4 z0 = *(const float4*)(zr + k + 0);
            float4 z1 = *(const float4*)(zr + k + 4);
            float4 z2 = *(const float4*)(zr + k + 8);
            float4 z3 = *(const float4*)(zr + k + 12);
            d0 += (double)z0.x * e0.x; d0 += (double)z0.y * e0.y;
            d0 += (double)z0.z * e0.z; d0 += (double)z0.w * e0.w;
            d1 += (double)z1.x * e1.x; d1 += (double)z1.y * e1.y;
            d1 += (double)z1.z * e1.z; d1 += (double)z1.w * e1.w;
            d2 += (double)z2.x * e2.x; d2 += (double)z2.y * e2.y;
            d2 += (double)z2.z * e2.z; d2 += (double)z2.w * e2.w;
            d3 += (double)z3.x * e3.x; d3 += (double)z3.y * e3.y;
            d3 += (double)z3.z * e3.z; d3 += (double)z3.w * e3.w;
            n0 += (double)e0.x * e0.x; n0 += (double)e0.y * e0.y;
            n0 += (double)e0.z * e0.z; n0 += (double)e0.w * e0.w;
            n1 += (double)e1.x * e1.x; n1 += (double)e1.y * e1.y;
            n1 += (double)e1.z * e1.z; n1 += (double)e1.w * e1.w;
            n2 += (double)e2.x * e2.x; n2 += (double)e2.y * e2.y;
            n2 += (double)e2.z * e2.z; n2 += (double)e2.w * e2.w;
            n3 += (double)e3.x * e3.x; n3 += (double)e3.y * e3.y;
            n3 += (double)e3.z * e3.z; n3 += (double)e3.w * e3.w;
        }
        double bs = ((d0 + d1) + (d2 + d3)) - 0.5 * ((n0 + n1) + (n2 + n3));
        int bi = idx;
#pragma unroll
        for (int m = 1; m <= 16; m <<= 1) {
            double osc = __shfl_xor(bs, m);
            int    obi = __shfl_xor(bi, m);
            if (osc > bs || (osc == bs && obi < bi)) { bs = osc; bi = obi; }
        }
        if (cc == 0) tok[il] = bi;
    }
    __syncthreads();

    // ================= P5: gather z_q -> eg (aliases zl) + out_zq =====
    {
        const int px = t >> 5, eq = t & 31;   // 512 threads = 16px x 32 quads
        *(float4*)&eg[px * ZL_STR + eq * 4] =
            *(const float4*)(emb + (size_t)tok[px] * NE + eq * 4);
    }
    __syncthreads();
    for (int idx = t; idx < NE * 16; idx += 512) {
        int e = idx >> 4, i = idx & 15;
        out_zq[((size_t)b * NE + e) * NS + s0 + i] = eg[i * ZL_STR + e];
    }
    // no barrier needed: P6 only reads eg (already fenced above)

    // ================= P6: post_conv ==================================
    {
        const int c  = t & 255;
        const int ph = t >> 8;          // px half: 0 -> 0..7, 1 -> 8..15
        const int pb = ph * 8;
        const float* wr = post_w + (size_t)c * NE;
        const float bias = post_b[c];
        float a0 = 0.f, a1 = 0.f, a2 = 0.f, a3 = 0.f;
        float a4 = 0.f, a5 = 0.f, a6 = 0.f, a7 = 0.f;
#pragma unroll 4
        for (int k = 0; k < NE; k += 4) {
            float4 w4 = *(const float4*)(wr + k);
            float4 q;
            q = *(const float4*)&eg[(pb + 0) * ZL_STR + k];
            a0 = fmaf(w4.x, q.x, fmaf(w4.y, q.y, fmaf(w4.z, q.z, fmaf(w4.w, q.w, a0))));
            q = *(const float4*)&eg[(pb + 1) * ZL_STR + k];
            a1 = fmaf(w4.x, q.x, fmaf(w4.y, q.y, fmaf(w4.z, q.z, fmaf(w4.w, q.w, a1))));
            q = *(const float4*)&eg[(pb + 2) * ZL_STR + k];
            a2 = fmaf(w4.x, q.x, fmaf(w4.y, q.y, fmaf(w4.z, q.z, fmaf(w4.w, q.w, a2))));
            q = *(const float4*)&eg[(pb + 3) * ZL_STR + k];
            a3 = fmaf(w4.x, q.x, fmaf(w4.y, q.y, fmaf(w4.z, q.z, fmaf(w4.w, q.w, a3))));
            q = *(const float4*)&eg[(pb + 4) * ZL_STR + k];
            a4 = fmaf(w4.x, q.x, fmaf(w4.y, q.y, fmaf(w4.z, q.z, fmaf(w4.w, q.w, a4))));
            q = *(const float4*)&eg[(pb + 5) * ZL_STR + k];
            a5 = fmaf(w4.x, q.x, fmaf(w4.y, q.y, fmaf(w4.z, q.z, fmaf(w4.w, q.w, a5))));
            q = *(const float4*)&eg[(pb + 6) * ZL_STR + k];
            a6 = fmaf(w4.x, q.x, fmaf(w4.y, q.y, fmaf(w4.z, q.z, fmaf(w4.w, q.w, a6))));
            q = *(const float4*)&eg[(pb + 7) * ZL_STR + k];
            a7 = fmaf(w4.x, q.x, fmaf(w4.y, q.y, fmaf(w4.z, q.z, fmaf(w4.w, q.w, a7))));
        }
        float4 lo = { a0 + bias, a1 + bias, a2 + bias, a3 + bias };
        float4 hi = { a4 + bias, a5 + bias, a6 + bias, a7 + bias };
        float* dst = out_rec + ((size_t)b * NC + c) * NS + s0 + pb;
        *(float4*)(dst + 0) = lo;
        *(float4*)(dst + 4) = hi;
    }
}

// ---------------------------------------------------------------------------
extern "C" void kernel_launch(void* const* d_in, const int* in_sizes, int n_in,
                              void* d_out, int out_size, void* d_ws, size_t ws_size,
                              hipStream_t stream)
{
    const float* z_e    = (const float*)d_in[0];
    const float* pre_w  = (const float*)d_in[1];
    const float* pre_b  = (const float*)d_in[2];
    const float* emb    = (const float*)d_in[3];
    const float* post_w = (const float*)d_in[4];
    const float* post_b = (const float*)d_in[5];

    // d_out: fp32 x 4194304 = (z 1048576 | z_q 1048576 | rec 2097152)
    float* out     = (float*)d_out;
    float* out_z   = out;
    float* out_zq  = out + 1048576;
    float* out_rec = out + 2097152;

    // Scratch: Bpack 1 MB + cnorm 16 KB in d_ws (fallback: rec head; the
    // d_ws path has always been taken in this harness, ws_size >= 2 MB).
    const size_t SZ_BPACK = (size_t)256 * 4 * 512 * 2;            // 1 MB
    const size_t SZ_CNORM = (size_t)NV * 4;                       // 16 KB
    const size_t NEED = SZ_BPACK + SZ_CNORM;
    char* scr = (ws_size >= NEED) ? (char*)d_ws : (char*)out_rec;
    ushort_t* Bpack = (ushort_t*)scr;
    float*    cnorm = (float*)(scr + SZ_BPACK);

    pack_emb<<<dim3(128), 256, 0, stream>>>(emb, Bpack, cnorm);
    vq_main <<<dim3(512), 512, 0, stream>>>(z_e, pre_w, pre_b, emb,
                                            post_w, post_b, Bpack, cnorm,
                                            out_z, out_zq, out_rec);
}

// Round 7
// 171.093 us; speedup vs baseline: 1.0562x; 1.0562x over previous
//
#include <hip/hip_runtime.h>
#include <hip/hip_bf16.h>
#include <cstdint>

// Problem constants
#define NB   32      // batch
#define NC   256     // z channels
#define NE   128     // embed dim
#define NS   256     // H*W pixels per batch
#define NV   4096    // vocab
#define NP   8192    // total pixels
#define NSPLIT 8     // vocab splits (512 codes each)

typedef unsigned short ushort_t;
typedef __attribute__((ext_vector_type(8))) short bf16x8;
typedef __attribute__((ext_vector_type(8))) unsigned short us8;
typedef __attribute__((ext_vector_type(4))) float f32x4;

__device__ __forceinline__ ushort_t f2bf(float f) {
    __hip_bfloat16 h = __float2bfloat16(f);
    ushort_t u; __builtin_memcpy(&u, &h, 2); return u;
}
__device__ __forceinline__ unsigned asu(float f) { unsigned u; __builtin_memcpy(&u,&f,4); return u; }
__device__ __forceinline__ float    asf(unsigned u) { float f; __builtin_memcpy(&f,&u,4); return f; }

// ---------------------------------------------------------------------------
// K0: pack emb hi-bf16 into Bpack (MFMA B-frag order) + cnorm. (Validated.)
// Bpack (ushort units): [(G*4 + ks)*512 + L*8 + j],
//   element = emb[code = G*16 + (L&15)][k = ks*32 + (L>>4)*8 + j]
// ---------------------------------------------------------------------------
__global__ __launch_bounds__(256) void pack_emb(
    const float* __restrict__ emb, ushort_t* __restrict__ Bpack,
    float* __restrict__ cnorm)
{
    const int t = threadIdx.x;
    const int v     = blockIdx.x * 32 + (t >> 3);
    const int chunk = t & 7;
    const float4* rp = (const float4*)(emb + (size_t)v * NE + chunk * 16);
    float4 x0 = rp[0], x1 = rp[1], x2 = rp[2], x3 = rp[3];
    float xs[16] = { x0.x, x0.y, x0.z, x0.w, x1.x, x1.y, x1.z, x1.w,
                     x2.x, x2.y, x2.z, x2.w, x3.x, x3.y, x3.z, x3.w };
    us8 h0, h1;
    float nn = 0.f;
#pragma unroll
    for (int j = 0; j < 8; j++) {
        nn = fmaf(xs[j], xs[j], nn);
        h0[j] = f2bf(xs[j]);
    }
#pragma unroll
    for (int j = 0; j < 8; j++) {
        nn = fmaf(xs[8 + j], xs[8 + j], nn);
        h1[j] = f2bf(xs[8 + j]);
    }
    nn += __shfl_xor(nn, 1);
    nn += __shfl_xor(nn, 2);
    nn += __shfl_xor(nn, 4);
    if (chunk == 0) cnorm[v] = 0.5f * nn;

    const int G  = v >> 4;
    const int ks = chunk >> 1;
    const int q0 = (chunk & 1) * 2;
    const int L0 = (v & 15) | (q0 << 4);
    const int L1 = (v & 15) | ((q0 + 1) << 4);
    *(us8*)(Bpack + ((size_t)G * 4 + ks) * 512 + L0 * 8) = h0;
    *(us8*)(Bpack + ((size_t)G * 4 + ks) * 512 + L1 * 8) = h1;
}

// ---------------------------------------------------------------------------
// K_main v3: whole pixel pipeline, 256 blocks x 1024 threads (16 waves,
// 1 block/CU -> 4 waves/SIMD). Round-6 lesson: P3's Bpack sweep is per-block
// (1 MB regardless of px), so occupancy must come from waves-per-block, not
// more blocks. 32 px/block keeps the total B-traffic at the round-5 level
// while doubling resident waves.
//   P1 stage z_e tile (ze[256][32], dense float4 copy)
//   P2 z-GEMM f32: thread=(pg = px-quad 0..7, e); zl[32][132] + out_z
//   P3 MFMA scoring, 4 splits in flight (wq=wave>>2), wv=wave&3 = validated
//      score_mfma layout (mt=2, cgi 0..7, same 9-bit encode); 2 sp-iters.
//      top-4/split -> cand[8][32][4]
//   P4 exact f64 rescore: 1 cand/thread (32px x 32cand = 1024), 4-way
//      partials, 32-lane shfl argmax, tie -> lowest idx
//   P5 gather z_q -> eg (aliases zl) + out_zq
//   P6 post_conv (c = t&255, ph = t>>8 -> 8 px each, one pass)
// LDS arena 96896 B (1 block/CU by design; gfx950 allows >64KB workgroups).
// ---------------------------------------------------------------------------
#define ZE_STR   32
#define ZL_STR   132
#define ZE_OFF   0           // 256*32*4 = 32768 (dead after P2)
#define R1_OFF   0           // 4*64*33*4 = 33792 (aliases ze union region)
#define ZL_OFF   33792       // 32*132*4 = 16896  (eg aliases after P4)
#define R2_OFF   50688       // 33792
#define T4B_OFF  84480       // 4*32*4*4*4 = 8192
#define CAND_OFF 92672       // 8*32*4*4 = 4096
#define TOK_OFF  96768       // 32*4 = 128
#define SM_SIZE  96896

__global__ __launch_bounds__(1024, 4) void vq_main(
    const float* __restrict__ z_e, const float* __restrict__ pre_w,
    const float* __restrict__ pre_b, const float* __restrict__ emb,
    const float* __restrict__ post_w, const float* __restrict__ post_b,
    const ushort_t* __restrict__ Bpack, const float* __restrict__ cnorm,
    float* __restrict__ out_z, float* __restrict__ out_zq,
    float* __restrict__ out_rec)
{
    __shared__ __align__(16) char smraw[SM_SIZE];
    float* ze   = (float*)(smraw + ZE_OFF);
    float* r1   = (float*)(smraw + R1_OFF);
    float* r2   = (float*)(smraw + R2_OFF);
    float* t4b  = (float*)(smraw + T4B_OFF);
    float* zl   = (float*)(smraw + ZL_OFF);
    float* eg   = (float*)(smraw + ZL_OFF);    // alias, used after P4
    int*   cand = (int*)(smraw + CAND_OFF);
    int*   tok  = (int*)(smraw + TOK_OFF);

    const int t  = threadIdx.x;
    const int b  = blockIdx.x >> 3;
    const int s0 = (blockIdx.x & 7) * 32;

    // ================= P1: stage z_e[b, :, s0..s0+32] (float4) ========
    for (int idx = t; idx < NC * 8; idx += 1024) {
        int c = idx >> 3, q = idx & 7;
        *(float4*)&ze[c * ZE_STR + q * 4] =
            *(const float4*)(z_e + ((size_t)b * NC + c) * NS + s0 + q * 4);
    }
    __syncthreads();

    // ================= P2: z-GEMM (f32) ===============================
    {
        const int pg = t >> 7;       // px quad 0..7
        const int e  = t & 127;      // embed row
        const float* wr = pre_w + (size_t)e * NC;
        float a0 = 0.f, a1 = 0.f, a2 = 0.f, a3 = 0.f;
#pragma unroll 2
        for (int c = 0; c < NC; c += 4) {
            float4 w4 = *(const float4*)(wr + c);
            float4 z4;
            z4 = *(const float4*)&ze[(c + 0) * ZE_STR + pg * 4];
            a0 = fmaf(w4.x, z4.x, a0); a1 = fmaf(w4.x, z4.y, a1);
            a2 = fmaf(w4.x, z4.z, a2); a3 = fmaf(w4.x, z4.w, a3);
            z4 = *(const float4*)&ze[(c + 1) * ZE_STR + pg * 4];
            a0 = fmaf(w4.y, z4.x, a0); a1 = fmaf(w4.y, z4.y, a1);
            a2 = fmaf(w4.y, z4.z, a2); a3 = fmaf(w4.y, z4.w, a3);
            z4 = *(const float4*)&ze[(c + 2) * ZE_STR + pg * 4];
            a0 = fmaf(w4.z, z4.x, a0); a1 = fmaf(w4.z, z4.y, a1);
            a2 = fmaf(w4.z, z4.z, a2); a3 = fmaf(w4.z, z4.w, a3);
            z4 = *(const float4*)&ze[(c + 3) * ZE_STR + pg * 4];
            a0 = fmaf(w4.w, z4.x, a0); a1 = fmaf(w4.w, z4.y, a1);
            a2 = fmaf(w4.w, z4.z, a2); a3 = fmaf(w4.w, z4.w, a3);
        }
        const float bias = pre_b[e];
        a0 += bias; a1 += bias; a2 += bias; a3 += bias;
        zl[(pg * 4 + 0) * ZL_STR + e] = a0;
        zl[(pg * 4 + 1) * ZL_STR + e] = a1;
        zl[(pg * 4 + 2) * ZL_STR + e] = a2;
        zl[(pg * 4 + 3) * ZL_STR + e] = a3;
        float4 o = { a0, a1, a2, a3 };
        *(float4*)(out_z + ((size_t)b * NE + e) * NS + s0 + pg * 4) = o;
    }
    __syncthreads();

    // ================= P3: MFMA scoring + top-4/split =================
    const int wave = t >> 6, lane = t & 63;
    const int am = lane & 15, aq = lane >> 4;

    // A-fragments (validated packing, mt=2 over 32 rows)
    bf16x8 ah[2][4];
#pragma unroll
    for (int mt = 0; mt < 2; mt++)
#pragma unroll
        for (int ks = 0; ks < 4; ks++) {
            const unsigned* src = (const unsigned*)(zl + (mt * 16 + am) * ZL_STR + ks * 32 + aq * 8);
            union { unsigned u[4]; bf16x8 v; } pk;
#pragma unroll
            for (int pr = 0; pr < 4; pr++)
                pk.u[pr] = (src[2 * pr + 1] & 0xFFFF0000u) | (src[2 * pr] >> 16);
            ah[mt][ks] = pk.v;
        }

    const int wq = wave >> 2;      // split within quad (4 in flight)
    const int wv = wave & 3;       // plays validated kernel's "wave"

    for (int sp = 0; sp < NSPLIT; sp += 4) {
        const int split = sp + wq;
        const int Gbase = split * 32 + wv * 8;
        float cn[8];
#pragma unroll
        for (int cgi = 0; cgi < 8; cgi++)
            cn[cgi] = cnorm[(Gbase + cgi) * 16 + am];

        float b1v[8], b2v[8];
#pragma unroll
        for (int i = 0; i < 8; i++) { b1v[i] = -1e30f; b2v[i] = -1e30f; }

        bf16x8 bh[4], bhn[4];
#pragma unroll
        for (int ks = 0; ks < 4; ks++)
            bh[ks] = *(const bf16x8*)(Bpack + ((size_t)Gbase * 4 + ks) * 512 + lane * 8);

        for (int cgi = 0; cgi < 8; cgi++) {
            if (cgi < 7) {
#pragma unroll
                for (int ks = 0; ks < 4; ks++)
                    bhn[ks] = *(const bf16x8*)(Bpack + ((size_t)(Gbase + cgi + 1) * 4 + ks) * 512 + lane * 8);
            }
            f32x4 acc[2];
#pragma unroll
            for (int mt = 0; mt < 2; mt++) acc[mt] = (f32x4){0.f, 0.f, 0.f, 0.f};
#pragma unroll
            for (int ks = 0; ks < 4; ks++)
#pragma unroll
                for (int mt = 0; mt < 2; mt++)
                    acc[mt] = __builtin_amdgcn_mfma_f32_16x16x32_bf16(ah[mt][ks], bh[ks], acc[mt], 0, 0, 0);

#pragma unroll
            for (int mt = 0; mt < 2; mt++)
#pragma unroll
                for (int reg = 0; reg < 4; reg++) {
                    const int si = mt * 4 + reg;
                    float sc = acc[mt][reg] - cn[cgi];
                    float ev = asf((asu(sc) & ~7u) | (unsigned)cgi);
                    b2v[si] = fmaxf(b2v[si], fminf(ev, b1v[si]));
                    b1v[si] = fmaxf(b1v[si], ev);
                }
#pragma unroll
            for (int ks = 0; ks < 4; ks++) bh[ks] = bhn[ks];
        }

        const int slot = wv * 16 + am;
#pragma unroll
        for (int mt = 0; mt < 2; mt++)
#pragma unroll
            for (int reg = 0; reg < 4; reg++) {
                int px = mt * 16 + aq * 4 + reg;
                r1[(wq * 64 + slot) * 33 + px] = b1v[mt * 4 + reg];
                r2[(wq * 64 + slot) * 33 + px] = b2v[mt * 4 + reg];
            }
        __syncthreads();

        if (t < 512) {
            const int wq2 = t >> 7, rem = t & 127;
            const int px = rem >> 2, ch = rem & 3;
            float t1 = -1e30f, t2 = -1e30f, t3 = -1e30f, t4 = -1e30f;
            for (int i = 0; i < 16; i++) {
                int sl = ch * 16 + i;
#pragma unroll
                for (int e = 0; e < 2; e++) {
                    float raw = e ? r2[(wq2 * 64 + sl) * 33 + px]
                                  : r1[(wq2 * 64 + sl) * 33 + px];
                    unsigned vb = asu(raw);
                    float v = asf((vb & ~511u) | ((unsigned)sl << 3) | (vb & 7u));
                    t4 = fmaxf(t4, fminf(v, t3));
                    t3 = fmaxf(t3, fminf(v, t2));
                    t2 = fmaxf(t2, fminf(v, t1));
                    t1 = fmaxf(t1, v);
                }
            }
            float* dst = t4b + ((wq2 * 32 + px) * 4 + ch) * 4;
            dst[0] = t1; dst[1] = t2; dst[2] = t3; dst[3] = t4;
        }
        __syncthreads();

        if (t < 128) {
            const int wq2 = t >> 5, px = t & 31;
            float u1 = -1e30f, u2 = -1e30f, u3 = -1e30f, u4 = -1e30f;
            for (int ch = 0; ch < 4; ch++) {
#pragma unroll
                for (int j = 0; j < 4; j++) {
                    float v = t4b[((wq2 * 32 + px) * 4 + ch) * 4 + j];
                    u4 = fmaxf(u4, fminf(v, u3));
                    u3 = fmaxf(u3, fminf(v, u2));
                    u2 = fmaxf(u2, fminf(v, u1));
                    u1 = fmaxf(u1, v);
                }
            }
            const int spw = sp + wq2;
            float uu[4] = { u1, u2, u3, u4 };
#pragma unroll
            for (int j = 0; j < 4; j++) {
                unsigned bits = asu(uu[j]) & 511u;
                int w = (int)(bits >> 7), res = (int)((bits >> 3) & 15u), cg = (int)(bits & 7u);
                cand[(spw * 32 + px) * 4 + j] = spw * 512 + (w * 8 + cg) * 16 + res;
            }
        }
        __syncthreads();
    }

    // ================= P4: exact f64 rescore (1 cand/thread) ==========
    {
        const int il = t >> 5;   // px 0..31
        const int cc = t & 31;   // candidate 0..31
        const int split = cc >> 2, slot = cc & 3;
        const int idx = cand[(split * 32 + il) * 4 + slot];
        const float* er = emb + (size_t)idx * NE;
        const float* zr = zl + il * ZL_STR;

        double d0 = 0.0, d1 = 0.0, d2 = 0.0, d3 = 0.0;
        double n0 = 0.0, n1 = 0.0, n2 = 0.0, n3 = 0.0;
#pragma unroll
        for (int k = 0; k < NE; k += 16) {
            float4 e0 = *(const float4*)(er + k + 0);
            float4 e1 = *(const float4*)(er + k + 4);
            float4 e2 = *(const float4*)(er + k + 8);
            float4 e3 = *(const float4*)(er + k + 12);
            float4 z0 = *(const float4*)(zr + k + 0);
            float4 z1 = *(const float4*)(zr + k + 4);
            float4 z2 = *(const float4*)(zr + k + 8);
            float4 z3 = *(const float4*)(zr + k + 12);
            d0 += (double)z0.x * e0.x; d0 += (double)z0.y * e0.y;
            d0 += (double)z0.z * e0.z; d0 += (double)z0.w * e0.w;
            d1 += (double)z1.x * e1.x; d1 += (double)z1.y * e1.y;
            d1 += (double)z1.z * e1.z; d1 += (double)z1.w * e1.w;
            d2 += (double)z2.x * e2.x; d2 += (double)z2.y * e2.y;
            d2 += (double)z2.z * e2.z; d2 += (double)z2.w * e2.w;
            d3 += (double)z3.x * e3.x; d3 += (double)z3.y * e3.y;
            d3 += (double)z3.z * e3.z; d3 += (double)z3.w * e3.w;
            n0 += (double)e0.x * e0.x; n0 += (double)e0.y * e0.y;
            n0 += (double)e0.z * e0.z; n0 += (double)e0.w * e0.w;
            n1 += (double)e1.x * e1.x; n1 += (double)e1.y * e1.y;
            n1 += (double)e1.z * e1.z; n1 += (double)e1.w * e1.w;
            n2 += (double)e2.x * e2.x; n2 += (double)e2.y * e2.y;
            n2 += (double)e2.z * e2.z; n2 += (double)e2.w * e2.w;
            n3 += (double)e3.x * e3.x; n3 += (double)e3.y * e3.y;
            n3 += (double)e3.z * e3.z; n3 += (double)e3.w * e3.w;
        }
        double bs = ((d0 + d1) + (d2 + d3)) - 0.5 * ((n0 + n1) + (n2 + n3));
        int bi = idx;
#pragma unroll
        for (int m = 1; m <= 16; m <<= 1) {
            double osc = __shfl_xor(bs, m);
            int    obi = __shfl_xor(bi, m);
            if (osc > bs || (osc == bs && obi < bi)) { bs = osc; bi = obi; }
        }
        if (cc == 0) tok[il] = bi;
    }
    __syncthreads();

    // ================= P5: gather z_q -> eg (aliases zl) + out_zq =====
    {
        const int px = t >> 5, eq = t & 31;   // 1024 = 32px x 32 quads
        *(float4*)&eg[px * ZL_STR + eq * 4] =
            *(const float4*)(emb + (size_t)tok[px] * NE + eq * 4);
    }
    __syncthreads();
    for (int idx = t; idx < NE * 32; idx += 1024) {
        int e = idx >> 5, i = idx & 31;
        out_zq[((size_t)b * NE + e) * NS + s0 + i] = eg[i * ZL_STR + e];
    }
    // no barrier needed: P6 only reads eg (already fenced above)

    // ================= P6: post_conv ==================================
    {
        const int c  = t & 255;
        const int ph = t >> 8;          // px group: 0..3 -> 8 px each
        const int pb = ph * 8;
        const float* wr = post_w + (size_t)c * NE;
        const float bias = post_b[c];
        float a0 = 0.f, a1 = 0.f, a2 = 0.f, a3 = 0.f;
        float a4 = 0.f, a5 = 0.f, a6 = 0.f, a7 = 0.f;
#pragma unroll 4
        for (int k = 0; k < NE; k += 4) {
            float4 w4 = *(const float4*)(wr + k);
            float4 q;
            q = *(const float4*)&eg[(pb + 0) * ZL_STR + k];
            a0 = fmaf(w4.x, q.x, fmaf(w4.y, q.y, fmaf(w4.z, q.z, fmaf(w4.w, q.w, a0))));
            q = *(const float4*)&eg[(pb + 1) * ZL_STR + k];
            a1 = fmaf(w4.x, q.x, fmaf(w4.y, q.y, fmaf(w4.z, q.z, fmaf(w4.w, q.w, a1))));
            q = *(const float4*)&eg[(pb + 2) * ZL_STR + k];
            a2 = fmaf(w4.x, q.x, fmaf(w4.y, q.y, fmaf(w4.z, q.z, fmaf(w4.w, q.w, a2))));
            q = *(const float4*)&eg[(pb + 3) * ZL_STR + k];
            a3 = fmaf(w4.x, q.x, fmaf(w4.y, q.y, fmaf(w4.z, q.z, fmaf(w4.w, q.w, a3))));
            q = *(const float4*)&eg[(pb + 4) * ZL_STR + k];
            a4 = fmaf(w4.x, q.x, fmaf(w4.y, q.y, fmaf(w4.z, q.z, fmaf(w4.w, q.w, a4))));
            q = *(const float4*)&eg[(pb + 5) * ZL_STR + k];
            a5 = fmaf(w4.x, q.x, fmaf(w4.y, q.y, fmaf(w4.z, q.z, fmaf(w4.w, q.w, a5))));
            q = *(const float4*)&eg[(pb + 6) * ZL_STR + k];
            a6 = fmaf(w4.x, q.x, fmaf(w4.y, q.y, fmaf(w4.z, q.z, fmaf(w4.w, q.w, a6))));
            q = *(const float4*)&eg[(pb + 7) * ZL_STR + k];
            a7 = fmaf(w4.x, q.x, fmaf(w4.y, q.y, fmaf(w4.z, q.z, fmaf(w4.w, q.w, a7))));
        }
        float4 lo = { a0 + bias, a1 + bias, a2 + bias, a3 + bias };
        float4 hi = { a4 + bias, a5 + bias, a6 + bias, a7 + bias };
        float* dst = out_rec + ((size_t)b * NC + c) * NS + s0 + pb;
        *(float4*)(dst + 0) = lo;
        *(float4*)(dst + 4) = hi;
    }
}

// ---------------------------------------------------------------------------
extern "C" void kernel_launch(void* const* d_in, const int* in_sizes, int n_in,
                              void* d_out, int out_size, void* d_ws, size_t ws_size,
                              hipStream_t stream)
{
    const float* z_e    = (const float*)d_in[0];
    const float* pre_w  = (const float*)d_in[1];
    const float* pre_b  = (const float*)d_in[2];
    const float* emb    = (const float*)d_in[3];
    const float* post_w = (const float*)d_in[4];
    const float* post_b = (const float*)d_in[5];

    // d_out: fp32 x 4194304 = (z 1048576 | z_q 1048576 | rec 2097152)
    float* out     = (float*)d_out;
    float* out_z   = out;
    float* out_zq  = out + 1048576;
    float* out_rec = out + 2097152;

    // Scratch: Bpack 1 MB + cnorm 16 KB in d_ws (fallback: rec head; the
    // d_ws path has always been taken in this harness, ws_size >= 2 MB).
    const size_t SZ_BPACK = (size_t)256 * 4 * 512 * 2;            // 1 MB
    const size_t SZ_CNORM = (size_t)NV * 4;                       // 16 KB
    const size_t NEED = SZ_BPACK + SZ_CNORM;
    char* scr = (ws_size >= NEED) ? (char*)d_ws : (char*)out_rec;
    ushort_t* Bpack = (ushort_t*)scr;
    float*    cnorm = (float*)(scr + SZ_BPACK);

    pack_emb<<<dim3(128), 256,  0, stream>>>(emb, Bpack, cnorm);
    vq_main <<<dim3(256), 1024, 0, stream>>>(z_e, pre_w, pre_b, emb,
                                             post_w, post_b, Bpack, cnorm,
                                             out_z, out_zq, out_rec);
}